// Round 13
// baseline (275.346 us; speedup 1.0000x reference)
//
#include <hip/hip_runtime.h>

// ChebGraphConv as ONE flat GEMM (K=192) over contiguous rows r = bt*1024+n:
//   out[r][o] = sum_{k,c} (d_k[n(r)] * x[r][c]) * Theta[k][c][o] + sum_k bias[k][o]
// R13 = R10 (best, 85.7us: 8-wave q-split, LDS x tiles, counted vmcnt+barrier,
// setprio, NT scattered stores) with an LDS DIET for 3 blocks/CU:
//   - 3 x-buffers (48KB) instead of 4 (64KB)
//   - diag scales in 24 registers (loaded in prologue, drained with vmcnt(0)
//     before the pipeline so the counted queue stays exactly stages+stores)
//   - dvs LDS buffer removed entirely
// -> LDS 48KB: 3 blocks/CU = 24 waves/CU (R10 had 2 blocks, occ 39%).
// R12's LDS pair-exchange epilogue REVERTED (WRITE 325MB, FETCH 188MB, 122us).
// B=32,T=24,N=1024 -> 786432 rows. C_IN=C_OUT=64, K_cheb=3.

#define NNODES 1024
#define TILE_ROWS 64
#define NT 8
#define ROWS_PER_BLOCK (TILE_ROWS * NT)         // 512
#define NBLOCKS (786432 / ROWS_PER_BLOCK)       // 1536

// ws layout
#define WS_W  0                  // 24 frags * 64 lanes * 16B = 24 KB (bf16)
#define WS_BS (24 * 1024)        // 64 * f32 summed bias
#define WS_DV (24 * 1024 + 256)  // 1024 * f32x4 {d0,d1,d2,0}

typedef __attribute__((ext_vector_type(8))) short short8;  // 8 x bf16 MFMA frag
typedef __attribute__((ext_vector_type(4))) float f32x4;   // MFMA C/D frag
typedef __attribute__((ext_vector_type(4))) int   i32x4;

// round-to-nearest-even f32 -> bf16 bits (prep kernel only)
__device__ __forceinline__ unsigned short f2bf(float f) {
    union { float f; unsigned u; } v; v.f = f;
    unsigned r = v.u + 0x7FFFu + ((v.u >> 16) & 1u);
    return (unsigned short)(r >> 16);
}

// pack 2 f32 -> 2 bf16 in one VALU op
__device__ __forceinline__ int cvt_pk_bf16(float lo, float hi) {
    int r;
    asm("v_cvt_pk_bf16_f32 %0, %1, %2" : "=v"(r) : "v"(lo), "v"(hi));
    return r;
}

// dense global->LDS: wave-uniform LDS base, lane l lands at base + l*16
__device__ __forceinline__ void gload_lds16(const void* g, void* l) {
    __builtin_amdgcn_global_load_lds(
        (const __attribute__((address_space(1))) void*)g,
        (__attribute__((address_space(3))) void*)l,
        16, 0, 0);
}

__global__ void cheb_prep(const float* __restrict__ Tks,
                          const float* __restrict__ Theta,
                          const float* __restrict__ bias,
                          unsigned char* __restrict__ ws) {
    const int b = blockIdx.x;
    const int l = threadIdx.x;   // 64 threads
    if (b < 24) {
        // frag f = (kc*2+h)*4 + nb ; lane l holds W^T row o = nb*16+(l&15),
        // k-slice c = h*32 + (l>>4)*8 + j  (A-operand layout, 16x16x32)
        const int kc = b >> 3, h = (b >> 2) & 1, nb = b & 3;
        const int o  = nb * 16 + (l & 15);
        const int cb = h * 32 + (l >> 4) * 8;
        unsigned short* dst = (unsigned short*)(ws + WS_W) + ((size_t)b * 64 + l) * 8;
        #pragma unroll
        for (int j = 0; j < 8; ++j)
            dst[j] = f2bf(Theta[kc * 4096 + (cb + j) * 64 + o]);
    } else if (b < 40) {
        const int n = (b - 24) * 64 + l;
        const size_t dg = (size_t)n * (NNODES + 1);
        f32x4 v;
        v[0] = Tks[dg];
        v[1] = Tks[(size_t)NNODES * NNODES + dg];
        v[2] = Tks[(size_t)2 * NNODES * NNODES + dg];
        v[3] = 0.0f;
        *((f32x4*)(ws + WS_DV) + n) = v;
    } else {
        float* bs = (float*)(ws + WS_BS);
        bs[l] = bias[l] + bias[64 + l] + bias[128 + l];
    }
}

__global__ __launch_bounds__(512, 6) void cheb_main(
    const float* __restrict__ x,          // [786432 * 64]
    const unsigned char* __restrict__ ws,
    float* __restrict__ out)              // [786432 * 64]
{
    __shared__ float xs[3][TILE_ROWS * 64];   // 3 x 16 KB swizzled x tiles

    const int tid  = threadIdx.x;
    const int wave = tid >> 6;    // 0..7
    const int lane = tid & 63;
    const int lrow = lane & 15;
    const int lgrp = lane >> 4;
    const int wr   = wave >> 1;   // row-group 0..3
    const int q    = wave & 1;    // o-half
    const size_t rowbase = (size_t)blockIdx.x * ROWS_PER_BLOCK;

    const unsigned short* wimg  = (const unsigned short*)(ws + WS_W);
    const float*          bsum  = (const float*)(ws + WS_BS);
    const f32x4*          dvec4 = (const f32x4*)(ws + WS_DV);

    // ---- prologue (fully drained before the pipeline starts) ----
    short8 wf[3][2][2];                   // 12 W-frags for this o-half (48 VGPR)
    #pragma unroll
    for (int kc = 0; kc < 3; ++kc)
        #pragma unroll
        for (int h = 0; h < 2; ++h)
            #pragma unroll
            for (int nb = 0; nb < 2; ++nb)
                wf[kc][h][nb] = *(const short8*)(
                    wimg + ((size_t)(((kc * 2 + h) * 4 + q * 2 + nb) * 64 + lane)) * 8);

    f32x4 bs4[2];
    #pragma unroll
    for (int nb = 0; nb < 2; ++nb)
        bs4[nb] = *(const f32x4*)(bsum + q * 32 + nb * 16 + lgrp * 4);

    // per-iter diag scales in registers (24 VGPR, static indices after unroll)
    float d0[NT], d1[NT], d2[NT];
    #pragma unroll
    for (int t = 0; t < NT; ++t) {
        const f32x4 dv = dvec4[(rowbase + t * TILE_ROWS + wr * 16 + lrow) & (NNODES - 1)];
        d0[t] = dv[0]; d1[t] = dv[1]; d2[t] = dv[2];
    }
    // drain ALL prologue vmem: the counted pipeline queue starts empty
    asm volatile("s_waitcnt vmcnt(0)" ::: "memory");
    __builtin_amdgcn_sched_barrier(0);

    // ---- STAGE tile T: 16 x 1KB chunks; wave stages chunks 2w,2w+1 ----
    // chunk u covers tile rows 4u..4u+3; lane l -> LDS byte u*1024 + l*16
    // = row (4u + l>>4), linear col (l&15)*16; source col ^= ((row&7)<<4)
#define STAGE(T) do { if ((T) < NT) {                                         \
        _Pragma("unroll")                                                     \
        for (int s = 0; s < 2; ++s) {                                         \
            const int u_ = wave * 2 + s;                                      \
            const int R_ = u_ * 4 + lgrp;                                     \
            const int c_ = (lrow * 16) ^ ((R_ & 7) << 4);                     \
            const char* g_ = (const char*)x +                                 \
                (((rowbase + (size_t)(T) * TILE_ROWS + R_) << 8) + c_);       \
            gload_lds16(g_, (char*)&xs[(T) % 3][0] + u_ * 1024);              \
        } } } while (0)

#define WAITV(N) do {                                                         \
        asm volatile("s_waitcnt vmcnt(" #N ")" ::: "memory");                 \
        __builtin_amdgcn_sched_barrier(0);                                    \
        __builtin_amdgcn_s_barrier();                                         \
        __builtin_amdgcn_sched_barrier(0);                                    \
    } while (0)

#define BODY(T) do {                                                          \
        const int m_ = (lrow & 7) << 4;                                       \
        const char* rowp = (const char*)&xs[(T) % 3][0]                       \
                         + (wr * 16 + lrow) * 256;                            \
        const int c00 = (lgrp * 32) ^ m_;                                     \
        const int c01 = (lgrp * 32 + 16) ^ m_;                                \
        const f32x4 x0 = *(const f32x4*)(rowp + c00);                         \
        const f32x4 x1 = *(const f32x4*)(rowp + c01);                         \
        const f32x4 x2 = *(const f32x4*)(rowp + 128 + c00);                   \
        const f32x4 x3 = *(const f32x4*)(rowp + 128 + c01);                   \
        const float dk0 = d0[T], dk1 = d1[T], dk2 = d2[T];                    \
        short8 xf[3][2];                                                      \
        _Pragma("unroll")                                                     \
        for (int kc = 0; kc < 3; ++kc) {                                      \
            const float dk = kc == 0 ? dk0 : (kc == 1 ? dk1 : dk2);           \
            i32x4 r0, r1;                                                     \
            r0[0] = cvt_pk_bf16(dk * x0[0], dk * x0[1]);                      \
            r0[1] = cvt_pk_bf16(dk * x0[2], dk * x0[3]);                      \
            r0[2] = cvt_pk_bf16(dk * x1[0], dk * x1[1]);                      \
            r0[3] = cvt_pk_bf16(dk * x1[2], dk * x1[3]);                      \
            r1[0] = cvt_pk_bf16(dk * x2[0], dk * x2[1]);                      \
            r1[1] = cvt_pk_bf16(dk * x2[2], dk * x2[3]);                      \
            r1[2] = cvt_pk_bf16(dk * x3[0], dk * x3[1]);                      \
            r1[3] = cvt_pk_bf16(dk * x3[2], dk * x3[3]);                      \
            xf[kc][0] = __builtin_bit_cast(short8, r0);                       \
            xf[kc][1] = __builtin_bit_cast(short8, r1);                       \
        }                                                                     \
        f32x4 acc[2] = {f32x4{0,0,0,0}, f32x4{0,0,0,0}};                      \
        __builtin_amdgcn_s_setprio(1);                                        \
        _Pragma("unroll")                                                     \
        for (int kc = 0; kc < 3; ++kc)                                        \
            _Pragma("unroll")                                                 \
            for (int h = 0; h < 2; ++h)                                       \
                _Pragma("unroll")                                             \
                for (int nb = 0; nb < 2; ++nb)                                \
                    acc[nb] = __builtin_amdgcn_mfma_f32_16x16x32_bf16(        \
                        wf[kc][h][nb], xf[kc][h], acc[nb], 0, 0, 0);          \
        __builtin_amdgcn_s_setprio(0);                                        \
        float* orow = out + (rowbase + (size_t)(T) * TILE_ROWS                \
                           + wr * 16 + lrow) * 64 + q * 32;                   \
        _Pragma("unroll")                                                     \
        for (int nb = 0; nb < 2; ++nb) {                                      \
            f32x4 o4;                                                         \
            _Pragma("unroll")                                                 \
            for (int j = 0; j < 4; ++j) o4[j] = acc[nb][j] + bs4[nb][j];      \
            __builtin_nontemporal_store(o4, (f32x4*)(orow + nb * 16 + lgrp * 4)); \
        }                                                                     \
    } while (0)

    // ---- pipeline: slot T = [WAITV(N); STAGE(T+2); BODY(T)], 3 buffers ----
    // exact N (2 stage-loads + 2 NT stores/slot): slot0=2, slot1=4, steady=4,
    // slot7=2; margined down where cheap -> {0,2,4,4,4,4,4,2}
    STAGE(0); STAGE(1);
    WAITV(0); STAGE(2); BODY(0);
    WAITV(2); STAGE(3); BODY(1);
    WAITV(4); STAGE(4); BODY(2);
    WAITV(4); STAGE(5); BODY(3);
    WAITV(4); STAGE(6); BODY(4);
    WAITV(4); STAGE(7); BODY(5);
    WAITV(4); STAGE(8); BODY(6);   // STAGE(8/9) compile out
    WAITV(2); STAGE(9); BODY(7);

#undef STAGE
#undef WAITV
#undef BODY
}

extern "C" void kernel_launch(void* const* d_in, const int* in_sizes, int n_in,
                              void* d_out, int out_size, void* d_ws, size_t ws_size,
                              hipStream_t stream) {
    const float* x     = (const float*)d_in[0];
    const float* Tks   = (const float*)d_in[1];
    const float* Theta = (const float*)d_in[2];
    const float* bias  = (const float*)d_in[3];
    float* out = (float*)d_out;
    unsigned char* ws = (unsigned char*)d_ws;

    hipLaunchKernelGGL(cheb_prep, dim3(41), dim3(64), 0, stream,
                       Tks, Theta, bias, ws);
    hipLaunchKernelGGL(cheb_main, dim3(NBLOCKS), dim3(512), 0, stream,
                       x, ws, out);
}

// Round 14
// 252.483 us; speedup vs baseline: 1.0905x; 1.0905x over previous
//
#include <hip/hip_runtime.h>

// ChebGraphConv as ONE flat GEMM (K=192) over contiguous rows r = bt*1024+n:
//   out[r][o] = sum_{k,c} (d_k[n(r)] * x[r][c]) * Theta[k][c][o] + sum_k bias[k][o]
// R14 = R10 (best, 85.7us) with a real LDS diet for 3 blocks/CU:
//   - 3 x-buffers (48KB), stage-ahead T+2 (R8/R11: depth-2 == depth-3)
//   - diag scales as bf16x4 LDS image (4KB staged from an 8KB ws image)
//   - launch_bounds(512,6): 24 waves/CU. R10's VGPR was 56 << 85 cap, so no
//     spill (R13 spilled because it ALSO moved diag into 24 registers).
// Everything else identical to R10: 8-wave q-split (12 W-frags/wave, 48 VGPR),
// gload_lds staging w/ pre-swizzled source, counted vmcnt + s_barrier,
// setprio around MFMA, NT scattered dwordx4 stores.
// B=32,T=24,N=1024 -> 786432 rows. C_IN=C_OUT=64, K_cheb=3.

#define NNODES 1024
#define TILE_ROWS 64
#define NT 8
#define ROWS_PER_BLOCK (TILE_ROWS * NT)         // 512
#define NBLOCKS (786432 / ROWS_PER_BLOCK)       // 1536

// ws layout
#define WS_W  0                  // 24 frags * 64 lanes * 16B = 24 KB (bf16)
#define WS_BS (24 * 1024)        // 64 * f32 summed bias
#define WS_DV (24 * 1024 + 256)  // 1024 nodes * 8B {bf16 d0,d1,d2,0}

typedef __attribute__((ext_vector_type(8))) short short8;  // 8 x bf16 MFMA frag
typedef __attribute__((ext_vector_type(4))) float f32x4;   // MFMA C/D frag
typedef __attribute__((ext_vector_type(4))) int   i32x4;
typedef __attribute__((ext_vector_type(2))) unsigned int u32x2;

// round-to-nearest-even f32 -> bf16 bits (prep kernel only)
__device__ __forceinline__ unsigned short f2bf(float f) {
    union { float f; unsigned u; } v; v.f = f;
    unsigned r = v.u + 0x7FFFu + ((v.u >> 16) & 1u);
    return (unsigned short)(r >> 16);
}

// pack 2 f32 -> 2 bf16 in one VALU op
__device__ __forceinline__ int cvt_pk_bf16(float lo, float hi) {
    int r;
    asm("v_cvt_pk_bf16_f32 %0, %1, %2" : "=v"(r) : "v"(lo), "v"(hi));
    return r;
}

// dense global->LDS: wave-uniform LDS base, lane l lands at base + l*16
__device__ __forceinline__ void gload_lds16(const void* g, void* l) {
    __builtin_amdgcn_global_load_lds(
        (const __attribute__((address_space(1))) void*)g,
        (__attribute__((address_space(3))) void*)l,
        16, 0, 0);
}

__global__ void cheb_prep(const float* __restrict__ Tks,
                          const float* __restrict__ Theta,
                          const float* __restrict__ bias,
                          unsigned char* __restrict__ ws) {
    const int b = blockIdx.x;
    const int l = threadIdx.x;   // 64 threads
    if (b < 24) {
        // frag f = (kc*2+h)*4 + nb ; lane l holds W^T row o = nb*16+(l&15),
        // k-slice c = h*32 + (l>>4)*8 + j  (A-operand layout, 16x16x32)
        const int kc = b >> 3, h = (b >> 2) & 1, nb = b & 3;
        const int o  = nb * 16 + (l & 15);
        const int cb = h * 32 + (l >> 4) * 8;
        unsigned short* dst = (unsigned short*)(ws + WS_W) + ((size_t)b * 64 + l) * 8;
        #pragma unroll
        for (int j = 0; j < 8; ++j)
            dst[j] = f2bf(Theta[kc * 4096 + (cb + j) * 64 + o]);
    } else if (b < 40) {
        const int n = (b - 24) * 64 + l;
        const size_t dg = (size_t)n * (NNODES + 1);
        unsigned short* dst = (unsigned short*)(ws + WS_DV) + (size_t)n * 4;
        dst[0] = f2bf(Tks[dg]);
        dst[1] = f2bf(Tks[(size_t)NNODES * NNODES + dg]);
        dst[2] = f2bf(Tks[(size_t)2 * NNODES * NNODES + dg]);
        dst[3] = 0;
    } else {
        float* bs = (float*)(ws + WS_BS);
        bs[l] = bias[l] + bias[64 + l] + bias[128 + l];
    }
}

__global__ __launch_bounds__(512, 6) void cheb_main(
    const float* __restrict__ x,          // [786432 * 64]
    const unsigned char* __restrict__ ws,
    float* __restrict__ out)              // [786432 * 64]
{
    __shared__ float xs[3][TILE_ROWS * 64];                // 48 KB swizzled x tiles
    __shared__ __align__(16) unsigned short dvs[ROWS_PER_BLOCK][4];  // 4 KB bf16 diag

    const int tid  = threadIdx.x;
    const int wave = tid >> 6;    // 0..7
    const int lane = tid & 63;
    const int lrow = lane & 15;
    const int lgrp = lane >> 4;
    const int wr   = wave >> 1;   // row-group 0..3
    const int q    = wave & 1;    // o-half
    const size_t rowbase = (size_t)blockIdx.x * ROWS_PER_BLOCK;

    const unsigned short* wimg = (const unsigned short*)(ws + WS_W);
    const float*          bsum = (const float*)(ws + WS_BS);

    // ---- prologue: all vmem here is OLDER than stage(0) -> first WAITV
    //      retires it before anything reads dvs ----
    short8 wf[3][2][2];                   // 12 W-frags for this o-half (48 VGPR)
    #pragma unroll
    for (int kc = 0; kc < 3; ++kc)
        #pragma unroll
        for (int h = 0; h < 2; ++h)
            #pragma unroll
            for (int nb = 0; nb < 2; ++nb)
                wf[kc][h][nb] = *(const short8*)(
                    wimg + ((size_t)(((kc * 2 + h) * 4 + q * 2 + nb) * 64 + lane)) * 8);

    f32x4 bs4[2];
    #pragma unroll
    for (int nb = 0; nb < 2; ++nb)
        bs4[nb] = *(const f32x4*)(bsum + q * 32 + nb * 16 + lgrp * 4);

    // stage bf16 diag image: waves 0-3 stage 1KB each (rows 128w..128w+127;
    // lane covers 2 rows x 8B). rowbase%1024 in {0,512} -> no wrap mid-chunk.
    if (wave < 4)
        gload_lds16((const char*)(ws + WS_DV)
                        + ((rowbase + wave * 128) & (NNODES - 1)) * 8 + lane * 16,
                    &dvs[wave * 128][0]);

    // ---- STAGE tile T: 16 x 1KB chunks; wave stages chunks 2w,2w+1 ----
    // chunk u covers tile rows 4u..4u+3; lane l -> LDS byte u*1024 + l*16
    // = row (4u + l>>4), linear col (l&15)*16; source col ^= ((row&7)<<4)
#define STAGE(T) do { if ((T) < NT) {                                         \
        _Pragma("unroll")                                                     \
        for (int s = 0; s < 2; ++s) {                                         \
            const int u_ = wave * 2 + s;                                      \
            const int R_ = u_ * 4 + lgrp;                                     \
            const int c_ = (lrow * 16) ^ ((R_ & 7) << 4);                     \
            const char* g_ = (const char*)x +                                 \
                (((rowbase + (size_t)(T) * TILE_ROWS + R_) << 8) + c_);       \
            gload_lds16(g_, (char*)&xs[(T) % 3][0] + u_ * 1024);              \
        } } } while (0)

#define WAITV(N) do {                                                         \
        asm volatile("s_waitcnt vmcnt(" #N ")" ::: "memory");                 \
        __builtin_amdgcn_sched_barrier(0);                                    \
        __builtin_amdgcn_s_barrier();                                         \
        __builtin_amdgcn_sched_barrier(0);                                    \
    } while (0)

#define BODY(T) do {                                                          \
        const int m_ = (lrow & 7) << 4;                                       \
        const char* rowp = (const char*)&xs[(T) % 3][0]                       \
                         + (wr * 16 + lrow) * 256;                            \
        const int c00 = (lgrp * 32) ^ m_;                                     \
        const int c01 = (lgrp * 32 + 16) ^ m_;                                \
        const f32x4 x0 = *(const f32x4*)(rowp + c00);                         \
        const f32x4 x1 = *(const f32x4*)(rowp + c01);                         \
        const f32x4 x2 = *(const f32x4*)(rowp + 128 + c00);                   \
        const f32x4 x3 = *(const f32x4*)(rowp + 128 + c01);                   \
        const u32x2 dw = *(const u32x2*)(&dvs[(T) * TILE_ROWS + wr * 16 + lrow][0]); \
        const float dk0 = __builtin_bit_cast(float, dw[0] << 16);             \
        const float dk1 = __builtin_bit_cast(float, dw[0] & 0xFFFF0000u);     \
        const float dk2 = __builtin_bit_cast(float, dw[1] << 16);             \
        short8 xf[3][2];                                                      \
        _Pragma("unroll")                                                     \
        for (int kc = 0; kc < 3; ++kc) {                                      \
            const float dk = kc == 0 ? dk0 : (kc == 1 ? dk1 : dk2);           \
            i32x4 r0, r1;                                                     \
            r0[0] = cvt_pk_bf16(dk * x0[0], dk * x0[1]);                      \
            r0[1] = cvt_pk_bf16(dk * x0[2], dk * x0[3]);                      \
            r0[2] = cvt_pk_bf16(dk * x1[0], dk * x1[1]);                      \
            r0[3] = cvt_pk_bf16(dk * x1[2], dk * x1[3]);                      \
            r1[0] = cvt_pk_bf16(dk * x2[0], dk * x2[1]);                      \
            r1[1] = cvt_pk_bf16(dk * x2[2], dk * x2[3]);                      \
            r1[2] = cvt_pk_bf16(dk * x3[0], dk * x3[1]);                      \
            r1[3] = cvt_pk_bf16(dk * x3[2], dk * x3[3]);                      \
            xf[kc][0] = __builtin_bit_cast(short8, r0);                       \
            xf[kc][1] = __builtin_bit_cast(short8, r1);                       \
        }                                                                     \
        f32x4 acc[2] = {f32x4{0,0,0,0}, f32x4{0,0,0,0}};                      \
        __builtin_amdgcn_s_setprio(1);                                        \
        _Pragma("unroll")                                                     \
        for (int kc = 0; kc < 3; ++kc)                                        \
            _Pragma("unroll")                                                 \
            for (int h = 0; h < 2; ++h)                                       \
                _Pragma("unroll")                                             \
                for (int nb = 0; nb < 2; ++nb)                                \
                    acc[nb] = __builtin_amdgcn_mfma_f32_16x16x32_bf16(        \
                        wf[kc][h][nb], xf[kc][h], acc[nb], 0, 0, 0);          \
        __builtin_amdgcn_s_setprio(0);                                        \
        float* orow = out + (rowbase + (size_t)(T) * TILE_ROWS                \
                           + wr * 16 + lrow) * 64 + q * 32;                   \
        _Pragma("unroll")                                                     \
        for (int nb = 0; nb < 2; ++nb) {                                      \
            f32x4 o4;                                                         \
            _Pragma("unroll")                                                 \
            for (int j = 0; j < 4; ++j) o4[j] = acc[nb][j] + bs4[nb][j];      \
            __builtin_nontemporal_store(o4, (f32x4*)(orow + nb * 16 + lgrp * 4)); \
        }                                                                     \
    } while (0)

    // ---- pipeline: slot T = [WAITV(N); STAGE(T+2); BODY(T)], 3 buffers ----
    // Exact queue (dvs gload oldest; 2 stage-loads + 2 NT stores per slot):
    // slot0: [dvs,s0,s0,s1,s1] -> vmcnt(2) retires dvs+s0. steady: vmcnt(6).
    STAGE(0); STAGE(1);
    WAITV(2); STAGE(2); BODY(0);
    WAITV(4); STAGE(3); BODY(1);
    WAITV(6); STAGE(4); BODY(2);
    WAITV(6); STAGE(5); BODY(3);
    WAITV(6); STAGE(6); BODY(4);
    WAITV(6); STAGE(7); BODY(5);
    WAITV(6); STAGE(8); BODY(6);   // STAGE(8/9) compile out
    WAITV(4); STAGE(9); BODY(7);

#undef STAGE
#undef WAITV
#undef BODY
}

extern "C" void kernel_launch(void* const* d_in, const int* in_sizes, int n_in,
                              void* d_out, int out_size, void* d_ws, size_t ws_size,
                              hipStream_t stream) {
    const float* x     = (const float*)d_in[0];
    const float* Tks   = (const float*)d_in[1];
    const float* Theta = (const float*)d_in[2];
    const float* bias  = (const float*)d_in[3];
    float* out = (float*)d_out;
    unsigned char* ws = (unsigned char*)d_ws;

    hipLaunchKernelGGL(cheb_prep, dim3(41), dim3(64), 0, stream,
                       Tks, Theta, bias, ws);
    hipLaunchKernelGGL(cheb_main, dim3(NBLOCKS), dim3(512), 0, stream,
                       x, ws, out);
}

// Round 17
// 85.231 us; speedup vs baseline: 3.2306x; 2.9623x over previous
//
#include <hip/hip_runtime.h>

// ChebGraphConv as ONE flat GEMM (K=192) over contiguous rows r = bt*1024+n:
//   out[r][o] = sum_{k,c} (d_k[n(r)] * x[r][c]) * Theta[k][c][o] + sum_k bias[k][o]
// R17 = EXACT REVERT TO R10 (best, 85.7us). The R15/R16 bpermute store-
// exchange failed correctness twice with an error I could not localize;
// reverting to the proven kernel. R10 structure:
//  - 8-wave (512-thr) blocks; wave (wr,q) computes 16 rows x 32 o-cols,
//    holding 12 W-frags (48 VGPR) -> VGPR 56 total, 2 blocks/CU
//  - x staged via global_load_lds width-16 (dense 1KB/instr), source
//    pre-swizzled (col ^= (row&7)<<4) for conflict-free swizzled ds_read_b128
//  - 4 LDS x-buffers, depth-3 stage-ahead, counted vmcnt(N) + s_barrier
//    (N never 0 in steady state: {2,4,6,6,6,6,6,4})
//  - s_setprio(1) around the MFMA cluster
//  - NON-TEMPORAL scattered dwordx4 stores (R10 vs R11 A/B: NT +5% net
//    despite +37% write bytes -- bypasses slow partial-line L2 merge path)
// B=32,T=24,N=1024 -> 786432 rows. C_IN=C_OUT=64, K_cheb=3.

#define NNODES 1024
#define TILE_ROWS 64
#define NT 8
#define ROWS_PER_BLOCK (TILE_ROWS * NT)         // 512
#define NBLOCKS (786432 / ROWS_PER_BLOCK)       // 1536

// ws layout
#define WS_W  0                  // 24 frags * 64 lanes * 16B = 24 KB (bf16)
#define WS_BS (24 * 1024)        // 64 * f32 summed bias
#define WS_DV (24 * 1024 + 256)  // 1024 * f32x4 {d0,d1,d2,0}

typedef __attribute__((ext_vector_type(8))) short short8;  // 8 x bf16 MFMA frag
typedef __attribute__((ext_vector_type(4))) float f32x4;   // MFMA C/D frag
typedef __attribute__((ext_vector_type(4))) int   i32x4;

// round-to-nearest-even f32 -> bf16 bits (prep kernel only)
__device__ __forceinline__ unsigned short f2bf(float f) {
    union { float f; unsigned u; } v; v.f = f;
    unsigned r = v.u + 0x7FFFu + ((v.u >> 16) & 1u);
    return (unsigned short)(r >> 16);
}

// pack 2 f32 -> 2 bf16 in one VALU op
__device__ __forceinline__ int cvt_pk_bf16(float lo, float hi) {
    int r;
    asm("v_cvt_pk_bf16_f32 %0, %1, %2" : "=v"(r) : "v"(lo), "v"(hi));
    return r;
}

// dense global->LDS: wave-uniform LDS base, lane l lands at base + l*16
__device__ __forceinline__ void gload_lds16(const void* g, void* l) {
    __builtin_amdgcn_global_load_lds(
        (const __attribute__((address_space(1))) void*)g,
        (__attribute__((address_space(3))) void*)l,
        16, 0, 0);
}

__global__ void cheb_prep(const float* __restrict__ Tks,
                          const float* __restrict__ Theta,
                          const float* __restrict__ bias,
                          unsigned char* __restrict__ ws) {
    const int b = blockIdx.x;
    const int l = threadIdx.x;   // 64 threads
    if (b < 24) {
        // frag f = (kc*2+h)*4 + nb ; lane l holds W^T row o = nb*16+(l&15),
        // k-slice c = h*32 + (l>>4)*8 + j  (A-operand layout, 16x16x32)
        const int kc = b >> 3, h = (b >> 2) & 1, nb = b & 3;
        const int o  = nb * 16 + (l & 15);
        const int cb = h * 32 + (l >> 4) * 8;
        unsigned short* dst = (unsigned short*)(ws + WS_W) + ((size_t)b * 64 + l) * 8;
        #pragma unroll
        for (int j = 0; j < 8; ++j)
            dst[j] = f2bf(Theta[kc * 4096 + (cb + j) * 64 + o]);
    } else if (b < 40) {
        const int n = (b - 24) * 64 + l;
        const size_t dg = (size_t)n * (NNODES + 1);
        f32x4 v;
        v[0] = Tks[dg];
        v[1] = Tks[(size_t)NNODES * NNODES + dg];
        v[2] = Tks[(size_t)2 * NNODES * NNODES + dg];
        v[3] = 0.0f;
        *((f32x4*)(ws + WS_DV) + n) = v;
    } else {
        float* bs = (float*)(ws + WS_BS);
        bs[l] = bias[l] + bias[64 + l] + bias[128 + l];
    }
}

__global__ __launch_bounds__(512, 4) void cheb_main(
    const float* __restrict__ x,          // [786432 * 64]
    const unsigned char* __restrict__ ws,
    float* __restrict__ out)              // [786432 * 64]
{
    __shared__ float xs[4][TILE_ROWS * 64];   // 4 x 16 KB swizzled x tiles
    __shared__ __align__(16) float dvs[ROWS_PER_BLOCK][4];  // 8 KB diag scales

    const int tid  = threadIdx.x;
    const int wave = tid >> 6;    // 0..7
    const int lane = tid & 63;
    const int lrow = lane & 15;
    const int lgrp = lane >> 4;
    const int wr   = wave >> 1;   // row-group 0..3
    const int q    = wave & 1;    // o-half
    const size_t rowbase = (size_t)blockIdx.x * ROWS_PER_BLOCK;

    const unsigned short* wimg = (const unsigned short*)(ws + WS_W);
    const float*          bsum = (const float*)(ws + WS_BS);
    const f32x4*          dvec = (const f32x4*)(ws + WS_DV);

    // ---- prologue: all vmem here is OLDER than stage(0) -> never affects N ----
    short8 wf[3][2][2];                   // 12 W-frags for this o-half (48 VGPR)
    #pragma unroll
    for (int kc = 0; kc < 3; ++kc)
        #pragma unroll
        for (int h = 0; h < 2; ++h)
            #pragma unroll
            for (int nb = 0; nb < 2; ++nb)
                wf[kc][h][nb] = *(const short8*)(
                    wimg + ((size_t)(((kc * 2 + h) * 4 + q * 2 + nb) * 64 + lane)) * 8);

    f32x4 bs4[2];
    #pragma unroll
    for (int nb = 0; nb < 2; ++nb)
        bs4[nb] = *(const f32x4*)(bsum + q * 32 + nb * 16 + lgrp * 4);

    // stage diag scales: wave w -> rows 64w..64w+63 (wave-private 1KB chunk)
    gload_lds16((const char*)dvec + (((rowbase + wave * 64) & (NNODES - 1)) * 16 + lane * 16),
                &dvs[wave * 64][0]);

    // ---- STAGE tile T: 16 x 1KB chunks; wave stages chunks 2w,2w+1 ----
    // chunk u covers tile rows 4u..4u+3; lane l -> LDS byte u*1024 + l*16
    // = row (4u + l>>4), linear col (l&15)*16; source col ^= ((row&7)<<4)
#define STAGE(T) do { if ((T) < NT) {                                         \
        _Pragma("unroll")                                                     \
        for (int s = 0; s < 2; ++s) {                                         \
            const int u_ = wave * 2 + s;                                      \
            const int R_ = u_ * 4 + lgrp;                                     \
            const int c_ = (lrow * 16) ^ ((R_ & 7) << 4);                     \
            const char* g_ = (const char*)x +                                 \
                (((rowbase + (size_t)(T) * TILE_ROWS + R_) << 8) + c_);       \
            gload_lds16(g_, (char*)&xs[(T) & 3][0] + u_ * 1024);              \
        } } } while (0)

#define WAITV(N) do {                                                         \
        asm volatile("s_waitcnt vmcnt(" #N ")" ::: "memory");                 \
        __builtin_amdgcn_sched_barrier(0);                                    \
        __builtin_amdgcn_s_barrier();                                         \
        __builtin_amdgcn_sched_barrier(0);                                    \
    } while (0)

#define BODY(T) do {                                                          \
        const int m_ = (lrow & 7) << 4;                                       \
        const char* rowp = (const char*)&xs[(T) & 3][0]                       \
                         + (wr * 16 + lrow) * 256;                            \
        const int c00 = (lgrp * 32) ^ m_;                                     \
        const int c01 = (lgrp * 32 + 16) ^ m_;                                \
        const f32x4 x0 = *(const f32x4*)(rowp + c00);                         \
        const f32x4 x1 = *(const f32x4*)(rowp + c01);                         \
        const f32x4 x2 = *(const f32x4*)(rowp + 128 + c00);                   \
        const f32x4 x3 = *(const f32x4*)(rowp + 128 + c01);                   \
        const f32x4 dv = *(const f32x4*)(&dvs[(T) * TILE_ROWS                 \
                                              + wr * 16 + lrow][0]);          \
        short8 xf[3][2];                                                      \
        _Pragma("unroll")                                                     \
        for (int kc = 0; kc < 3; ++kc) {                                      \
            const float dk = dv[kc];                                          \
            i32x4 r0, r1;                                                     \
            r0[0] = cvt_pk_bf16(dk * x0[0], dk * x0[1]);                      \
            r0[1] = cvt_pk_bf16(dk * x0[2], dk * x0[3]);                      \
            r0[2] = cvt_pk_bf16(dk * x1[0], dk * x1[1]);                      \
            r0[3] = cvt_pk_bf16(dk * x1[2], dk * x1[3]);                      \
            r1[0] = cvt_pk_bf16(dk * x2[0], dk * x2[1]);                      \
            r1[1] = cvt_pk_bf16(dk * x2[2], dk * x2[3]);                      \
            r1[2] = cvt_pk_bf16(dk * x3[0], dk * x3[1]);                      \
            r1[3] = cvt_pk_bf16(dk * x3[2], dk * x3[3]);                      \
            xf[kc][0] = __builtin_bit_cast(short8, r0);                       \
            xf[kc][1] = __builtin_bit_cast(short8, r1);                       \
        }                                                                     \
        f32x4 acc[2] = {f32x4{0,0,0,0}, f32x4{0,0,0,0}};                      \
        __builtin_amdgcn_s_setprio(1);                                        \
        _Pragma("unroll")                                                     \
        for (int kc = 0; kc < 3; ++kc)                                        \
            _Pragma("unroll")                                                 \
            for (int h = 0; h < 2; ++h)                                       \
                _Pragma("unroll")                                             \
                for (int nb = 0; nb < 2; ++nb)                                \
                    acc[nb] = __builtin_amdgcn_mfma_f32_16x16x32_bf16(        \
                        wf[kc][h][nb], xf[kc][h], acc[nb], 0, 0, 0);          \
        __builtin_amdgcn_s_setprio(0);                                        \
        float* orow = out + (rowbase + (size_t)(T) * TILE_ROWS                \
                           + wr * 16 + lrow) * 64 + q * 32;                   \
        _Pragma("unroll")                                                     \
        for (int nb = 0; nb < 2; ++nb) {                                      \
            f32x4 o4;                                                         \
            _Pragma("unroll")                                                 \
            for (int j = 0; j < 4; ++j) o4[j] = acc[nb][j] + bs4[nb][j];      \
            __builtin_nontemporal_store(o4, (f32x4*)(orow + nb * 16 + lgrp * 4)); \
        }                                                                     \
    } while (0)

    // ---- pipeline: depth-3 stage-ahead, 4 buffers ----
    // exact queue (2 stage-loads + 2 nt-stores per iter): N={4,6,8,...,8,6};
    // -2 safety margin -> {2,4,6,6,6,6,6,4}
    STAGE(0); STAGE(1); STAGE(2);
    WAITV(2); STAGE(3);  BODY(0);
    WAITV(4); STAGE(4);  BODY(1);
    WAITV(6); STAGE(5);  BODY(2);
    WAITV(6); STAGE(6);  BODY(3);
    WAITV(6); STAGE(7);  BODY(4);
    WAITV(6); STAGE(8);  BODY(5);   // STAGE(8..10) compile out
    WAITV(6); STAGE(9);  BODY(6);
    WAITV(4); STAGE(10); BODY(7);

#undef STAGE
#undef WAITV
#undef BODY
}

extern "C" void kernel_launch(void* const* d_in, const int* in_sizes, int n_in,
                              void* d_out, int out_size, void* d_ws, size_t ws_size,
                              hipStream_t stream) {
    const float* x     = (const float*)d_in[0];
    const float* Tks   = (const float*)d_in[1];
    const float* Theta = (const float*)d_in[2];
    const float* bias  = (const float*)d_in[3];
    float* out = (float*)d_out;
    unsigned char* ws = (unsigned char*)d_ws;

    hipLaunchKernelGGL(cheb_prep, dim3(41), dim3(64), 0, stream,
                       Tks, Theta, bias, ws);
    hipLaunchKernelGGL(cheb_main, dim3(NBLOCKS), dim3(512), 0, stream,
                       x, ws, out);
}